// Round 4
// baseline (337.481 us; speedup 1.0000x reference)
//
#include <hip/hip_runtime.h>

#define N_NODES 50000
#define N_EDGES 800000
#define IN_DIM 128
#define HID_DIM 256
#define OUT_DIM 2

// ---------------------------------------------------------------------------
// CSR build: histogram -> 3-step parallel scan -> reorder
// ---------------------------------------------------------------------------
__global__ __launch_bounds__(256) void k_hist(const int* __restrict__ ei,
                                              int* __restrict__ deg)
{
    int e = blockIdx.x * 256 + threadIdx.x;
    if (e < N_EDGES) atomicAdd(&deg[ei[N_EDGES + e]], 1);
}

__global__ __launch_bounds__(256) void k_scan_blk(const int* __restrict__ deg,
                                                  int* __restrict__ row_ptr,
                                                  int* __restrict__ partials)
{
    __shared__ int wsum[4];
    const int tid = threadIdx.x, lane = tid & 63, wave = tid >> 6;
    int i = blockIdx.x * 256 + tid;
    int v = (i < N_NODES) ? deg[i] : 0;
    int s = v;
#pragma unroll
    for (int off = 1; off < 64; off <<= 1) {
        int t = __shfl_up(s, off, 64);
        if (lane >= off) s += t;
    }
    if (lane == 63) wsum[wave] = s;
    __syncthreads();
    int wexcl = 0;
    for (int w = 0; w < wave; w++) wexcl += wsum[w];
    if (i < N_NODES) row_ptr[i] = wexcl + s - v;   // exclusive within block
    if (tid == 255) partials[blockIdx.x] = wexcl + s;
}

__global__ __launch_bounds__(256) void k_scan_top(const int* __restrict__ partials,
                                                  int* __restrict__ offsets,
                                                  int nblk)
{
    __shared__ int wsum[4];
    const int tid = threadIdx.x, lane = tid & 63, wave = tid >> 6;
    int v = (tid < nblk) ? partials[tid] : 0;
    int s = v;
#pragma unroll
    for (int off = 1; off < 64; off <<= 1) {
        int t = __shfl_up(s, off, 64);
        if (lane >= off) s += t;
    }
    if (lane == 63) wsum[wave] = s;
    __syncthreads();
    int wexcl = 0;
    for (int w = 0; w < wave; w++) wexcl += wsum[w];
    offsets[tid] = wexcl + s - v;                  // exclusive block offsets
}

__global__ __launch_bounds__(256) void k_scan_add(int* __restrict__ row_ptr,
                                                  const int* __restrict__ offsets,
                                                  int* __restrict__ cursor)
{
    int i = blockIdx.x * 256 + threadIdx.x;
    if (i < N_NODES) {
        int r = row_ptr[i] + offsets[blockIdx.x];
        row_ptr[i] = r;
        cursor[i]  = r;
    }
    if (i == 0) row_ptr[N_NODES] = N_EDGES;
}

__global__ __launch_bounds__(256) void k_reorder(const int* __restrict__ ei,
                                                 int* __restrict__ cursor,
                                                 int* __restrict__ csr_src)
{
    int e = blockIdx.x * 256 + threadIdx.x;
    if (e < N_EDGES) {
        int dst = ei[N_EDGES + e];
        int pos = atomicAdd(&cursor[dst], 1);
        csr_src[pos] = ei[e];
    }
}

// ---------------------------------------------------------------------------
// XCD-sliced pull-aggregate:  aggz = (1+e1)*x + sum_{src} x[src]
// slice = blockIdx.x & 7  ->  round-robin block->XCD mapping pins cols
// [16s,16s+16) (3.2 MB fp32) into ONE XCD's 4 MB L2 -> gather is L2-hot.
// 256 thr = 4 waves, 8 nodes/wave.  Lane = (nbr q 0..15) x (col-quad u 0..3):
// 16 neighbor float4 row-slice loads in flight per iteration.
// ---------------------------------------------------------------------------
__global__ __launch_bounds__(256) void k_agg(
    const float* __restrict__ x, const int* __restrict__ row_ptr,
    const int* __restrict__ csr_src, const float* __restrict__ eps1p,
    float* __restrict__ aggz)
{
    const int tid   = threadIdx.x;
    const int lane  = tid & 63;
    const int wv    = tid >> 6;
    const int slice = blockIdx.x & 7;
    const int chunk = blockIdx.x >> 3;
    const int q     = lane >> 2;          // neighbor sub-index 0..15
    const int u     = lane & 3;           // column quad 0..3
    const int col   = slice * 16 + 4 * u;
    const float e1  = 1.0f + eps1p[0];

    for (int nn = 0; nn < 8; nn++) {
        int node = chunk * 32 + wv * 8 + nn;      // wave-uniform
        if (node >= N_NODES) break;
        int beg = row_ptr[node], end = row_ptr[node + 1];
        float4 acc = make_float4(0.f, 0.f, 0.f, 0.f);
        for (int b = beg; b < end; b += 64) {
            int cnt = min(64, end - b);
            int srcs = csr_src[b + ((lane < cnt) ? lane : 0)];
            for (int g0 = 0; g0 < cnt; g0 += 16) {
                int idx = g0 + q;
                int sq = __shfl(srcs, (idx < cnt) ? idx : 0, 64);
                float4 v = *(const float4*)(x + (size_t)sq * IN_DIM + col);
                if (idx < cnt) {
                    acc.x += v.x; acc.y += v.y; acc.z += v.z; acc.w += v.w;
                }
            }
        }
        // reduce across the 16 neighbor groups
#pragma unroll
        for (int off = 4; off <= 32; off <<= 1) {
            acc.x += __shfl_xor(acc.x, off, 64);
            acc.y += __shfl_xor(acc.y, off, 64);
            acc.z += __shfl_xor(acc.z, off, 64);
            acc.w += __shfl_xor(acc.w, off, 64);
        }
        if (q == 0) {   // lanes 0..3 write the 16 columns
            float4 xv = *(const float4*)(x + (size_t)node * IN_DIM + col);
            float4 o;
            o.x = fmaf(e1, xv.x, acc.x);
            o.y = fmaf(e1, xv.y, acc.y);
            o.z = fmaf(e1, xv.z, acc.z);
            o.w = fmaf(e1, xv.w, acc.w);
            *(float4*)(aggz + (size_t)node * IN_DIM + col) = o;
        }
    }
}

// ---------------------------------------------------------------------------
// MLP: h = relu(aggz @ W1 + b1);  p = h @ W2
// 256 thr = 4 waves, 32-node tile, 8 nodes/wave; thread owns 4 W1 columns.
// ---------------------------------------------------------------------------
__global__ __launch_bounds__(256) void k_mlp(
    const float* __restrict__ aggz,
    const float* __restrict__ W1, const float* __restrict__ b1,
    const float* __restrict__ W2,
    float* __restrict__ p)
{
    __shared__ float z[32][IN_DIM];   // 16 KB
    const int tid  = threadIdx.x;
    const int lane = tid & 63;
    const int wv   = tid >> 6;
    const int node0 = blockIdx.x * 32;

    // cooperative stage (coalesced float4)
    for (int i = tid; i < 32 * (IN_DIM / 4); i += 256) {
        int n = i / (IN_DIM / 4);
        int c = i % (IN_DIM / 4);
        int node = node0 + n;
        float4 v = make_float4(0.f, 0.f, 0.f, 0.f);
        if (node < N_NODES)
            v = ((const float4*)(aggz + (size_t)node * IN_DIM))[c];
        ((float4*)&z[n][0])[c] = v;
    }
    __syncthreads();

    float4 b1v = *(const float4*)(b1 + 4 * lane);
    float4 acc[8];
#pragma unroll
    for (int nn = 0; nn < 8; nn++) acc[nn] = b1v;

    for (int k4 = 0; k4 < IN_DIM / 4; k4++) {
        float4 w0 = *(const float4*)(W1 + (size_t)(4 * k4 + 0) * HID_DIM + 4 * lane);
        float4 w1 = *(const float4*)(W1 + (size_t)(4 * k4 + 1) * HID_DIM + 4 * lane);
        float4 w2 = *(const float4*)(W1 + (size_t)(4 * k4 + 2) * HID_DIM + 4 * lane);
        float4 w3 = *(const float4*)(W1 + (size_t)(4 * k4 + 3) * HID_DIM + 4 * lane);
#pragma unroll
        for (int nn = 0; nn < 8; nn++) {
            float4 zv = *(const float4*)&z[8 * wv + nn][4 * k4];   // LDS broadcast
            acc[nn].x = fmaf(zv.x, w0.x, fmaf(zv.y, w1.x, fmaf(zv.z, w2.x, fmaf(zv.w, w3.x, acc[nn].x))));
            acc[nn].y = fmaf(zv.x, w0.y, fmaf(zv.y, w1.y, fmaf(zv.z, w2.y, fmaf(zv.w, w3.y, acc[nn].y))));
            acc[nn].z = fmaf(zv.x, w0.z, fmaf(zv.y, w1.z, fmaf(zv.z, w2.z, fmaf(zv.w, w3.z, acc[nn].z))));
            acc[nn].w = fmaf(zv.x, w0.w, fmaf(zv.y, w1.w, fmaf(zv.z, w2.w, fmaf(zv.w, w3.w, acc[nn].w))));
        }
    }

    // ReLU + W2 dot + 64-lane butterfly
    float2 w20 = *(const float2*)(W2 + (size_t)(4 * lane + 0) * OUT_DIM);
    float2 w21 = *(const float2*)(W2 + (size_t)(4 * lane + 1) * OUT_DIM);
    float2 w22 = *(const float2*)(W2 + (size_t)(4 * lane + 2) * OUT_DIM);
    float2 w23 = *(const float2*)(W2 + (size_t)(4 * lane + 3) * OUT_DIM);

#pragma unroll
    for (int nn = 0; nn < 8; nn++) {
        float h0 = fmaxf(acc[nn].x, 0.f);
        float h1 = fmaxf(acc[nn].y, 0.f);
        float h2 = fmaxf(acc[nn].z, 0.f);
        float h3 = fmaxf(acc[nn].w, 0.f);
        float px = h0 * w20.x + h1 * w21.x + h2 * w22.x + h3 * w23.x;
        float py = h0 * w20.y + h1 * w21.y + h2 * w22.y + h3 * w23.y;
#pragma unroll
        for (int off = 32; off >= 1; off >>= 1) {
            px += __shfl_xor(px, off, 64);
            py += __shfl_xor(py, off, 64);
        }
        int node = node0 + 8 * wv + nn;
        if (lane == 0 && node < N_NODES) {
            p[(size_t)node * OUT_DIM + 0] = px;
            p[(size_t)node * OUT_DIM + 1] = py;
        }
    }
}

// ---------------------------------------------------------------------------
// Layer 2 pull: out[n] = (1+e2)*p[n] + b2 + sum_{src in row n} p[src]
// 8 lanes per node: coalesced csr reads, shfl-xor group reduction.
// ---------------------------------------------------------------------------
__global__ __launch_bounds__(256) void k_out(
    const int* __restrict__ row_ptr, const int* __restrict__ csr_src,
    const float* __restrict__ p, const float* __restrict__ b2,
    const float* __restrict__ eps2p, float* __restrict__ out)
{
    const int tid  = threadIdx.x;
    const int lane = tid & 63;
    const int wv   = tid >> 6;
    const int node = blockIdx.x * 32 + wv * 8 + (lane >> 3);
    const int l    = lane & 7;
    if (node >= N_NODES) return;          // whole 8-lane group exits together
    int beg = row_ptr[node], end = row_ptr[node + 1];
    float sx = 0.f, sy = 0.f;
    for (int j = beg + l; j < end; j += 8) {
        int src = csr_src[j];
        float2 v = *(const float2*)(p + (size_t)src * OUT_DIM);
        sx += v.x; sy += v.y;
    }
#pragma unroll
    for (int off = 1; off <= 4; off <<= 1) {   // reduce within 8-lane group
        sx += __shfl_xor(sx, off, 64);
        sy += __shfl_xor(sy, off, 64);
    }
    if (l == 0) {
        float e2 = 1.0f + eps2p[0];
        float2 pv = *(const float2*)(p + (size_t)node * OUT_DIM);
        out[(size_t)node * OUT_DIM + 0] = fmaf(e2, pv.x, sx) + b2[0];
        out[(size_t)node * OUT_DIM + 1] = fmaf(e2, pv.y, sy) + b2[1];
    }
}

extern "C" void kernel_launch(void* const* d_in, const int* in_sizes, int n_in,
                              void* d_out, int out_size, void* d_ws, size_t ws_size,
                              hipStream_t stream)
{
    const float* x    = (const float*)d_in[0];
    const int*   ei   = (const int*)d_in[1];
    const float* W1   = (const float*)d_in[2];
    const float* b1   = (const float*)d_in[3];
    const float* W2   = (const float*)d_in[4];
    const float* b2   = (const float*)d_in[5];
    const float* eps1 = (const float*)d_in[6];
    const float* eps2 = (const float*)d_in[7];
    float* out = (float*)d_out;

    // workspace layout (all segments 16B-aligned)
    int* deg      = (int*)d_ws;                  // 50048
    int* row_ptr  = deg + 50048;                 // 50056 (N_NODES+1)
    int* cursor   = row_ptr + 50056;             // 50048
    int* partials = cursor + 50048;              // 256
    int* offsets  = partials + 256;              // 256
    int* csr_src  = offsets + 256;               // 800000
    float* p      = (float*)(csr_src + 800000);  // 100000
    float* aggz   = p + 100000;                  // 6400000 (25.6 MB)

    const int SCAN_BLKS = (N_NODES + 255) / 256;       // 196
    const int NODE_BLKS = (N_NODES + 31) / 32;         // 1563

    hipMemsetAsync(deg, 0, 50000 * sizeof(int), stream);
    k_hist<<<(N_EDGES + 255) / 256, 256, 0, stream>>>(ei, deg);
    k_scan_blk<<<SCAN_BLKS, 256, 0, stream>>>(deg, row_ptr, partials);
    k_scan_top<<<1, 256, 0, stream>>>(partials, offsets, SCAN_BLKS);
    k_scan_add<<<SCAN_BLKS, 256, 0, stream>>>(row_ptr, offsets, cursor);
    k_reorder<<<(N_EDGES + 255) / 256, 256, 0, stream>>>(ei, cursor, csr_src);
    k_agg<<<NODE_BLKS * 8, 256, 0, stream>>>(x, row_ptr, csr_src, eps1, aggz);
    k_mlp<<<NODE_BLKS, 256, 0, stream>>>(aggz, W1, b1, W2, p);
    k_out<<<NODE_BLKS, 256, 0, stream>>>(row_ptr, csr_src, p, b2, eps2, out);
}

// Round 6
// 294.679 us; speedup vs baseline: 1.1453x; 1.1453x over previous
//
#include <hip/hip_runtime.h>

#define N_NODES 50000
#define N_EDGES 800000
#define IN_DIM 128
#define HID_DIM 256
#define OUT_DIM 2

typedef __attribute__((ext_vector_type(8))) short bh8;   // 8 bf16 (A/B frag)
typedef __attribute__((ext_vector_type(4))) float f4;    // C/D frag

__device__ inline unsigned bf16rne(float f) {
    unsigned u = __float_as_uint(f);
    return (u + 0x7fffu + ((u >> 16) & 1u)) >> 16;
}

// ---------------------------------------------------------------------------
// k_prep: x->bf16x2, W1->B-fragment-packed bf16, zero deg + scan descriptors.
// Index space: [0, 3.2M) x-cvt | [..+16384) W1 pack | [..+50000) deg |
//              [..+256) desc.   (R5 bug: x-cvt range was half of x.)
// W1p layout: for n-tile t(0..15), k-step s(0..3), lane l, dword d(0..3):
//   lo = W1[32s+8*(l>>4)+2d][16t+(l&15)], hi = same k+1  -> one dwordx4/lane.
// ---------------------------------------------------------------------------
#define XCVT_N   3200000
#define W1P_END  (XCVT_N + 16384)
#define DEG_END  (W1P_END + 50000)
#define DESC_END (DEG_END + 256)

__global__ __launch_bounds__(256) void k_prep(
    const float* __restrict__ x, const float* __restrict__ W1,
    unsigned* __restrict__ xb, unsigned* __restrict__ W1p,
    int* __restrict__ deg, unsigned long long* __restrict__ desc)
{
    int i = blockIdx.x * 256 + threadIdx.x;
    if (i < XCVT_N) {
        float2 v = ((const float2*)x)[i];
        xb[i] = (bf16rne(v.y) << 16) | bf16rne(v.x);
    } else if (i < W1P_END) {
        int j = i - XCVT_N;
        int d = j & 3, l = (j >> 2) & 63, s = (j >> 8) & 3, t = j >> 10;
        int k = 32 * s + 8 * (l >> 4) + 2 * d;
        int n = 16 * t + (l & 15);
        W1p[j] = (bf16rne(W1[(size_t)(k + 1) * HID_DIM + n]) << 16)
               |  bf16rne(W1[(size_t)k * HID_DIM + n]);
    } else if (i < DEG_END) {
        deg[i - W1P_END] = 0;
    } else if (i < DESC_END) {
        desc[i - DEG_END] = 0ULL;
    }
}

// ---------------------------------------------------------------------------
// k_hist: in-degree histogram
// ---------------------------------------------------------------------------
__global__ __launch_bounds__(256) void k_hist(const int* __restrict__ ei,
                                              int* __restrict__ deg)
{
    int e = blockIdx.x * 256 + threadIdx.x;
    if (e < N_EDGES) atomicAdd(&deg[ei[N_EDGES + e]], 1);
}

// ---------------------------------------------------------------------------
// k_scan: single-pass decoupled-lookback exclusive scan (196 blocks, all
// co-resident). desc[b] = flag<<32 | sum; 1=aggregate, 2=inclusive-prefix.
// Communication is value-carried through single-address device atomics.
// ---------------------------------------------------------------------------
__global__ __launch_bounds__(256) void k_scan(
    const int* __restrict__ deg, unsigned long long* __restrict__ desc,
    int* __restrict__ row_ptr, int* __restrict__ cursor)
{
    __shared__ int wsum[4];
    __shared__ int s_prefix;
    const int tid = threadIdx.x, lane = tid & 63, wv = tid >> 6;
    const int b = blockIdx.x;
    int i = b * 256 + tid;
    int v = (i < N_NODES) ? deg[i] : 0;
    int s = v;
#pragma unroll
    for (int off = 1; off < 64; off <<= 1) {
        int t = __shfl_up(s, off, 64);
        if (lane >= off) s += t;
    }
    if (lane == 63) wsum[wv] = s;
    __syncthreads();
    int wexcl = 0;
    for (int w = 0; w < wv; w++) wexcl += wsum[w];
    int aggregate = wsum[0] + wsum[1] + wsum[2] + wsum[3];

    if (tid == 0) {
        if (b == 0) {
            atomicExch(&desc[0], (2ULL << 32) | (unsigned)aggregate);
            s_prefix = 0;
        } else {
            atomicExch(&desc[b], (1ULL << 32) | (unsigned)aggregate);
            int prefix = 0;
            int pb = b - 1;
            while (true) {
                unsigned long long st = atomicAdd(&desc[pb], 0ULL);
                unsigned flag = (unsigned)(st >> 32);
                if (flag == 0u) continue;
                prefix += (int)(unsigned)st;
                if (flag == 2u) break;
                pb--;
            }
            atomicExch(&desc[b], (2ULL << 32) | (unsigned)(prefix + aggregate));
            s_prefix = prefix;
        }
    }
    __syncthreads();
    int r = s_prefix + wexcl + s - v;
    if (i < N_NODES) { row_ptr[i] = r; cursor[i] = r; }
    if (b == gridDim.x - 1 && tid == 255) row_ptr[N_NODES] = s_prefix + aggregate;
}

// ---------------------------------------------------------------------------
// k_reorder: bucket src by dst
// ---------------------------------------------------------------------------
__global__ __launch_bounds__(256) void k_reorder(const int* __restrict__ ei,
                                                 int* __restrict__ cursor,
                                                 int* __restrict__ csr_src)
{
    int e = blockIdx.x * 256 + threadIdx.x;
    if (e < N_EDGES) {
        int dst = ei[N_EDGES + e];
        int pos = atomicAdd(&cursor[dst], 1);
        csr_src[pos] = ei[e];
    }
}

// ---------------------------------------------------------------------------
// k_gin1 (fused): per-wave 16-node m-tile, fully wave-private (NO barriers):
//  A) bf16 row gather (16 loads in flight/lane), fp32 acc, +(1+e1)x fp32,
//     round to bf16 -> LDS z16[16 nodes][68 dwords]
//  B) A-frags from LDS (A[m=lane&15][k=quad*8+j], k packed 2/dword);
//     B-frags coalesced dwordx4 from pre-packed W1p (64 KB, L2-hot);
//     64x mfma_f32_16x16x32_bf16 -> acc[16 n-tiles] (fp32)
//  C) +b1, ReLU, dot W2 in-lane, butterfly over 16-lane col group;
//     C row=(lane>>4)*4+reg -> node = node0+q*4+r.  Writes p and
//     out_init = (1+e2)p + b2.
// ---------------------------------------------------------------------------
__global__ __launch_bounds__(256) void k_gin1(
    const float* __restrict__ x, const unsigned* __restrict__ xb,
    const int* __restrict__ row_ptr, const int* __restrict__ csr_src,
    const unsigned* __restrict__ W1p, const float* __restrict__ b1,
    const float* __restrict__ W2, const float* __restrict__ b2,
    const float* __restrict__ eps1p, const float* __restrict__ eps2p,
    float* __restrict__ p, float* __restrict__ out)
{
    __shared__ unsigned z16[4][16 * 68];
    const int tid = threadIdx.x, lane = tid & 63, wv = tid >> 6;
    const int node0 = blockIdx.x * 64 + wv * 16;
    const float e1 = 1.0f + eps1p[0];

    // ---- Phase A: gather ----
    for (int nn = 0; nn < 16; nn++) {
        int node = node0 + nn;
        float ax = 0.f, ay = 0.f;
        if (node < N_NODES) {
            int beg = row_ptr[node], end = row_ptr[node + 1];
            for (int bb = beg; bb < end; bb += 64) {
                int cnt = min(64, end - bb);
                int srcs = csr_src[bb + ((lane < cnt) ? lane : 0)];
                for (int j0 = 0; j0 < cnt; j0 += 16) {
                    unsigned u[16];
#pragma unroll
                    for (int g = 0; g < 16; g++) {
                        int idx = j0 + g;
                        int sq = __shfl(srcs, (idx < cnt) ? idx : 0, 64);
                        u[g] = xb[(size_t)sq * 64 + lane];
                    }
#pragma unroll
                    for (int g = 0; g < 16; g++) {
                        if (j0 + g < cnt) {
                            ax += __uint_as_float(u[g] << 16);
                            ay += __uint_as_float(u[g] & 0xffff0000u);
                        }
                    }
                }
            }
            float2 xv = *(const float2*)(x + (size_t)node * IN_DIM + 2 * lane);
            ax = fmaf(e1, xv.x, ax);
            ay = fmaf(e1, xv.y, ay);
        }
        z16[wv][nn * 68 + lane] = (bf16rne(ay) << 16) | bf16rne(ax);
    }
    // wave-private: no __syncthreads

    // ---- Phase B: MFMA GEMM1 ----
    const int q = lane >> 4, c = lane & 15;
    bh8 afrag[4];
#pragma unroll
    for (int s = 0; s < 4; s++)
        afrag[s] = *(const bh8*)&z16[wv][c * 68 + 16 * s + 4 * q];

    f4 acc[16];
#pragma unroll
    for (int t = 0; t < 16; t++) acc[t] = (f4){0.f, 0.f, 0.f, 0.f};

#pragma unroll
    for (int t = 0; t < 16; t++) {
#pragma unroll
        for (int s = 0; s < 4; s++) {
            bh8 bfrag = *(const bh8*)(W1p + ((size_t)(t * 4 + s) * 64 + lane) * 4);
            acc[t] = __builtin_amdgcn_mfma_f32_16x16x32_bf16(afrag[s], bfrag, acc[t], 0, 0, 0);
        }
    }

    // ---- Phase C: bias + ReLU + W2 + butterfly + store ----
    const float e2 = 1.0f + eps2p[0];
    float pxr[4] = {0.f, 0.f, 0.f, 0.f};
    float pyr[4] = {0.f, 0.f, 0.f, 0.f};
#pragma unroll
    for (int t = 0; t < 16; t++) {
        int n = 16 * t + c;
        float bb = b1[n];
        float2 w2 = *(const float2*)(W2 + (size_t)n * OUT_DIM);
#pragma unroll
        for (int r = 0; r < 4; r++) {
            float h = fmaxf(acc[t][r] + bb, 0.f);
            pxr[r] = fmaf(h, w2.x, pxr[r]);
            pyr[r] = fmaf(h, w2.y, pyr[r]);
        }
    }
#pragma unroll
    for (int off = 1; off < 16; off <<= 1) {
#pragma unroll
        for (int r = 0; r < 4; r++) {
            pxr[r] += __shfl_xor(pxr[r], off, 64);
            pyr[r] += __shfl_xor(pyr[r], off, 64);
        }
    }
    if (c == 0) {
        float2 b2v = *(const float2*)b2;
#pragma unroll
        for (int r = 0; r < 4; r++) {
            int node = node0 + q * 4 + r;
            if (node < N_NODES) {
                *(float2*)(p + (size_t)node * OUT_DIM) = make_float2(pxr[r], pyr[r]);
                float2 o;
                o.x = fmaf(e2, pxr[r], b2v.x);
                o.y = fmaf(e2, pyr[r], b2v.y);
                *(float2*)(out + (size_t)node * OUT_DIM) = o;
            }
        }
    }
}

// ---------------------------------------------------------------------------
// k_out: out[n] += sum_{src in row n} p[src]   (out pre-init by k_gin1)
// 8 lanes per node, coalesced csr reads, shfl group reduce.
// ---------------------------------------------------------------------------
__global__ __launch_bounds__(256) void k_out(
    const int* __restrict__ row_ptr, const int* __restrict__ csr_src,
    const float* __restrict__ p, float* __restrict__ out)
{
    const int tid = threadIdx.x, lane = tid & 63, wv = tid >> 6;
    const int node = blockIdx.x * 32 + wv * 8 + (lane >> 3);
    const int l = lane & 7;
    if (node >= N_NODES) return;
    int beg = row_ptr[node], end = row_ptr[node + 1];
    float sx = 0.f, sy = 0.f;
    for (int j = beg + l; j < end; j += 8) {
        int src = csr_src[j];
        float2 v = *(const float2*)(p + (size_t)src * OUT_DIM);
        sx += v.x; sy += v.y;
    }
#pragma unroll
    for (int off = 1; off <= 4; off <<= 1) {
        sx += __shfl_xor(sx, off, 64);
        sy += __shfl_xor(sy, off, 64);
    }
    if (l == 0) {
        float2 o = *(const float2*)(out + (size_t)node * OUT_DIM);
        o.x += sx; o.y += sy;
        *(float2*)(out + (size_t)node * OUT_DIM) = o;
    }
}

extern "C" void kernel_launch(void* const* d_in, const int* in_sizes, int n_in,
                              void* d_out, int out_size, void* d_ws, size_t ws_size,
                              hipStream_t stream)
{
    const float* x    = (const float*)d_in[0];
    const int*   ei   = (const int*)d_in[1];
    const float* W1   = (const float*)d_in[2];
    const float* b1   = (const float*)d_in[3];
    const float* W2   = (const float*)d_in[4];
    const float* b2   = (const float*)d_in[5];
    const float* eps1 = (const float*)d_in[6];
    const float* eps2 = (const float*)d_in[7];
    float* out = (float*)d_out;

    // workspace layout
    int* deg                 = (int*)d_ws;                          // 50048
    unsigned long long* desc = (unsigned long long*)(deg + 50048);  // 256
    int* row_ptr             = (int*)(desc + 256);                  // 50056
    int* cursor              = row_ptr + 50056;                     // 50048
    int* csr_src             = cursor + 50048;                      // 800000
    float* p                 = (float*)(csr_src + 800000);          // 100000
    unsigned* xb             = (unsigned*)(p + 100000);             // 3200000
    unsigned* W1p            = xb + 3200000;                        // 16384

    k_prep<<<(DESC_END + 255) / 256, 256, 0, stream>>>(x, W1, xb, W1p, deg, desc);
    k_hist<<<(N_EDGES + 255) / 256, 256, 0, stream>>>(ei, deg);
    k_scan<<<196, 256, 0, stream>>>(deg, desc, row_ptr, cursor);
    k_reorder<<<(N_EDGES + 255) / 256, 256, 0, stream>>>(ei, cursor, csr_src);
    k_gin1<<<(N_NODES + 63) / 64, 256, 0, stream>>>(
        x, xb, row_ptr, csr_src, W1p, b1, W2, b2, eps1, eps2, p, out);
    k_out<<<(N_NODES + 31) / 32, 256, 0, stream>>>(row_ptr, csr_src, p, out);
}